// Round 1
// 128.876 us; speedup vs baseline: 1.0038x; 1.0038x over previous
//
#include <hip/hip_runtime.h>
#include <stdint.h>

// Problem constants (match reference)
#define HH 512
#define WW 512
#define CC 3
#define KK 32
#define SS 4
#define PP 10
#define NPATCH 126            // (512 + 20 - 32)/4 + 1
#define NP2 (NPATCH * NPATCH) // 15876
#define DD 3072               // C*K*K
#define NMEM 4096
#define THRESHV 0.5f

// ws layout (32-bit words). HARDENING RULE: every word read by a LATER
// kernel is UNCONDITIONALLY written by an earlier kernel on every launch.
// fallback scratch (OFF_FBSCR) is same-kernel, same-block write-then-read
// only (no cross-kernel, no cross-block), so poisoning cannot leak in.
#define OFF_PNORM  0          // 15876 f: per-patch ||u||^2        (K1 patch blocks)
#define OFF_PRMAX  16384      // 126 f: per-patch-row max pnorm    (K1 patch blocks)
#define OFF_PRMIN  16640      // 126 f: per-patch-row min pnorm    (K1 patch blocks)
#define OFF_NBMIN  16896      // 1024 f: per-block min mem-norm^2  (K1 norm blocks)
#define OFF_NBMAX  17920      // 1024 f: per-block max mem-norm^2  (K1 norm blocks)
#define OFF_PMAXA  18944      // 1024 f: per-block fold max        (K1 norm blocks)
#define OFF_FBSCR  262144     // fallback scratch: 1024 blocks * 2*15876 u32 (~124 MB)

__device__ inline float wave_max(float v) {
    for (int off = 32; off; off >>= 1) v = fmaxf(v, __shfl_xor(v, off, 64));
    return v;
}
__device__ inline float wave_min(float v) {
    for (int off = 32; off; off >>= 1) v = fminf(v, __shfl_xor(v, off, 64));
    return v;
}
__device__ inline float wave_sum(float v) {
    for (int off = 32; off; off >>= 1) v += __shfl_xor(v, off, 64);
    return v;
}

// Coverage count along one axis: # patch positions i with i*S <= v+P <= i*S+K-1
__device__ inline int cov1(int v) {
    int pv = v + PP;
    int a = pv - (KK - 1);
    int imin = (a <= 0) ? 0 : ((a + SS - 1) >> 2);
    int imax = pv >> 2;
    if (imax > NPATCH - 1) imax = NPATCH - 1;
    return imax - imin + 1;
}

// Kernel 1 (1150 blocks x 256):
//  blocks 0..125    : per-patch ||u||^2 for patch-row py=b (separable column
//                     window-sums) + per-row min/max. Scheduled FIRST so this
//                     L2-bound work overlaps the 48 MB mem read, not tails it.
//  blocks 126..1149 : mem row norms (4 rows/block, 12x float4) -> per-block
//                     min/max; certified fold max (img*cov_y*cov_x, NO store).
__global__ void fused_main(const float* __restrict__ mem,
                           const float* __restrict__ img,
                           float* __restrict__ pnorm,
                           float* __restrict__ prmax,
                           float* __restrict__ prmin,
                           float* __restrict__ nbmin,
                           float* __restrict__ nbmax,
                           float* __restrict__ pmaxA) {
    __shared__ float cs[WW];   // patch path: column sums
    __shared__ float sA[4], sB[4], sC[4];
    int b = blockIdx.x, tid = threadIdx.x;
    int lane = tid & 63, w = tid >> 6;

    if (b < NPATCH) {
        int py = b;
        int y0 = py * SS - PP;
        float s0 = 0.f, s1 = 0.f;
        int x0c = tid, x1c = tid + 256;
#pragma unroll
        for (int ky = 0; ky < KK; ++ky) {
            int y = y0 + ky;
            if (y >= 0 && y < HH) {
                const float* row = img + (size_t)y * WW * CC;
                const float* p0 = row + x0c * CC;
                const float* p1 = row + x1c * CC;
                s0 += p0[0] * p0[0] + p0[1] * p0[1] + p0[2] * p0[2];
                s1 += p1[0] * p1[0] + p1[1] * p1[1] + p1[2] * p1[2];
            }
        }
        cs[x0c] = s0;
        cs[x1c] = s1;
        __syncthreads();
        float t = 0.f;
        if (tid < NPATCH) {
            int x0 = tid * SS - PP;
#pragma unroll
            for (int kx = 0; kx < KK; ++kx) {
                int xx = x0 + kx;
                if (xx >= 0 && xx < WW) t += cs[xx];
            }
            pnorm[py * NPATCH + tid] = t;
        }
        float tmax = (tid < NPATCH) ? t : -INFINITY;
        float tmin = (tid < NPATCH) ? t : INFINITY;
        tmax = wave_max(tmax);
        tmin = wave_min(tmin);
        if (lane == 0) { sA[w] = tmax; sB[w] = tmin; }
        __syncthreads();
        if (tid == 0) {
            prmax[py] = fmaxf(fmaxf(sA[0], sA[1]), fmaxf(sA[2], sA[3]));
            prmin[py] = fminf(fminf(sB[0], sB[1]), fminf(sB[2], sB[3]));
        }
        return;
    }

    int b2 = b - NPATCH;  // 0..1023

    // ---- fold-max part (threads 0..191; 1024*192 float4 == H*W*C/4) ----
    float m = -INFINITY;
    if (tid < 192) {
        int f = b2 * 192 + tid;
        float4 v = ((const float4*)img)[f];
        float r[4] = {v.x, v.y, v.z, v.w};
        int e = f * 4;
#pragma unroll
        for (int k = 0; k < 4; ++k) {
            int px = (e + k) / 3;
            int y = px >> 9, x = px & 511;
            m = fmaxf(m, r[k] * (float)(cov1(y) * cov1(x)));
        }
    }

    // ---- mem norms (all 4 waves, one row each) ----
    int row = b2 * 4 + w;
    const float4* rp = (const float4*)(mem + (size_t)row * DD); // 768 f4/row
    float4 v[12];
#pragma unroll
    for (int i = 0; i < 12; ++i) v[i] = rp[lane + (i << 6)];
    float s0 = 0.f, s1 = 0.f, s2 = 0.f, s3 = 0.f;
#pragma unroll
    for (int i = 0; i < 12; ++i) {
        s0 += v[i].x * v[i].x; s1 += v[i].y * v[i].y;
        s2 += v[i].z * v[i].z; s3 += v[i].w * v[i].w;
    }
    float s = wave_sum((s0 + s1) + (s2 + s3));

    m = wave_max(m);
    if (lane == 0) { sA[w] = m; sB[w] = s; }
    __syncthreads();
    if (tid == 0) {
        pmaxA[b2] = fmaxf(fmaxf(sA[0], sA[1]), fmaxf(sA[2], sA[3]));
        nbmin[b2] = fminf(fminf(sB[0], sB[1]), fminf(sB[2], sB[3]));
        nbmax[b2] = fmaxf(fmaxf(sB[0], sB[1]), fmaxf(sB[2], sB[3]));
    }
    (void)sC;
}

// Exact fixed-output value for element i (fallback path only).
__device__ float fixed_val(int i, const float* __restrict__ img,
                           const float* __restrict__ mem2,
                           const uint32_t* __restrict__ scr, uint32_t nr) {
    int px = i / 3, ch = i - px * 3;
    int y = px >> 9, x = px & 511;
    float base = img[i];
    float v = base * (float)(cov1(y) * cov1(x));
    for (uint32_t e = 0; e < nr; ++e) {
        int p = (int)scr[2 * e];
        int pi = p / NPATCH, pj = p % NPATCH;
        int ky = y - (pi * SS - PP), kx = x - (pj * SS - PP);
        if (ky >= 0 && ky < KK && kx >= 0 && kx < KK) {
            const float* rec = mem2 + (size_t)scr[2 * e + 1] * DD;
            v += rec[(ch << 10) + (ky << 5) + kx] - base;
        }
    }
    return v;
}

// Kernel 2 (1024 blocks x 256): certification + normalize, fused.
// Every block redundantly reduces the unconditionally-written partials
// (L2-hot, ~14 KB) to the identical block-uniform verdict:
//   certified <=> (min||m|| - max||u||)^2 >= THRESH  (or the symmetric side).
// Certified (always in practice): out slice = img * cov * inv, written ONCE,
// never read. Fallback (never taken): each block redundantly computes exact
// fixes into its PRIVATE ws scratch (same-block write-then-read only), a
// redundant global max, then its own exact slice. Correct for any input.
__global__ void finish_k(const float* __restrict__ img,
                         const float* __restrict__ mem,
                         const float* __restrict__ mem2,
                         const long long* __restrict__ mapping,
                         const float* __restrict__ pnorm,
                         const float* __restrict__ prmax,
                         const float* __restrict__ prmin,
                         const float* __restrict__ nbmin,
                         const float* __restrict__ nbmax,
                         const float* __restrict__ pmaxA,
                         float* __restrict__ out,
                         uint32_t* __restrict__ fbscr) {
    __shared__ float r0[4], r1[4], r2[4], r3[4], r4[4];
    __shared__ float s_lo, s_hi, s_inv;
    __shared__ int s_cert;
    int tid = threadIdx.x, lane = tid & 63, w = tid >> 6;

    float lo2 = INFINITY, hi2 = -INFINITY, bmax = -INFINITY;
#pragma unroll
    for (int k = 0; k < 4; ++k) {
        int i = tid + (k << 8);
        lo2 = fminf(lo2, nbmin[i]);
        hi2 = fmaxf(hi2, nbmax[i]);
        bmax = fmaxf(bmax, pmaxA[i]);
    }
    float up2 = (tid < NPATCH) ? prmax[tid] : -INFINITY;
    float un2 = (tid < NPATCH) ? prmin[tid] : INFINITY;

    lo2 = wave_min(lo2); hi2 = wave_max(hi2); bmax = wave_max(bmax);
    up2 = wave_max(up2); un2 = wave_min(un2);
    if (lane == 0) { r0[w] = lo2; r1[w] = hi2; r2[w] = bmax; r3[w] = up2; r4[w] = un2; }
    __syncthreads();
    if (tid == 0) {
        float a = fminf(fminf(r0[0], r0[1]), fminf(r0[2], r0[3]));
        float bb = fmaxf(fmaxf(r1[0], r1[1]), fmaxf(r1[2], r1[3]));
        float c = fmaxf(fmaxf(r2[0], r2[1]), fmaxf(r2[2], r2[3]));
        float d = fmaxf(fmaxf(r3[0], r3[1]), fmaxf(r3[2], r3[3]));
        float e = fminf(fminf(r4[0], r4[1]), fminf(r4[2], r4[3]));
        float lo = sqrtf(a), hi = sqrtf(bb);
        float umax = sqrtf(d), umin = sqrtf(e);
        int cert = 0;
        if (umax <= lo) { float g = lo - umax; if (g * g >= THRESHV) cert = 1; }
        if (!cert && umin >= hi) { float g = umin - hi; if (g * g >= THRESHV) cert = 1; }
        s_cert = cert; s_lo = lo; s_hi = hi; s_inv = 1.0f / c;
    }
    __syncthreads();

    if (s_cert) {   // block-uniform AND grid-consistent (identical inputs/ops)
        float inv = s_inv;
        if (tid < 192) {
            int f = blockIdx.x * 192 + tid;   // 1024*192 float4 == H*W*C/4
            float4 v = ((const float4*)img)[f];
            float r[4] = {v.x, v.y, v.z, v.w};
            int e = f * 4;
#pragma unroll
            for (int k = 0; k < 4; ++k) {
                int px = (e + k) / 3;
                int y = px >> 9, x = px & 511;
                r[k] *= (float)(cov1(y) * cov1(x)) * inv;
            }
            float4 o; o.x = r[0]; o.y = r[1]; o.z = r[2]; o.w = r[3];
            ((float4*)out)[f] = o;
        }
        return;
    }

    // ---------------- fallback (never taken in practice) ----------------
    __shared__ float smin[256];
    __shared__ int sarg[256];
    __shared__ uint32_t s_nr;
    __shared__ float s_ginv;
    float lo = s_lo, hi = s_hi;
    uint32_t* myscr = fbscr + (size_t)blockIdx.x * (2u * NP2);
    if (tid == 0) s_nr = 0;
    __syncthreads();

    for (int p = 0; p < NP2; ++p) {
        float un = sqrtf(pnorm[p]);
        float gap = 0.f;
        if (un <= lo) gap = lo - un;
        else if (un >= hi) gap = un - hi;
        if (gap * gap >= THRESHV) continue;   // block-uniform

        int pi = p / NPATCH, pj = p % NPATCH;
        int y0 = pi * SS - PP, x0 = pj * SS - PP;
        float best = INFINITY; int barg = NMEM;
        for (int j = tid; j < NMEM; j += 256) {
            const float* mr = mem + (size_t)j * DD;
            float acc = 0.f;
            for (int d = 0; d < DD; ++d) {
                int c = d >> 10, rem = d & 1023, ky = rem >> 5, kx = rem & 31;
                int y = y0 + ky, x = x0 + kx;
                float u = (y >= 0 && y < HH && x >= 0 && x < WW)
                              ? img[((size_t)y * WW + x) * CC + c] : 0.f;
                float dif = u - mr[d];
                acc += dif * dif;
            }
            if (acc < best) { best = acc; barg = j; }
        }
        smin[tid] = best; sarg[tid] = barg;
        __syncthreads();
        for (int st = 128; st; st >>= 1) {
            if (tid < st) {
                float s2 = smin[tid + st];
                int a2 = sarg[tid + st];
                if (s2 < smin[tid] || (s2 == smin[tid] && a2 < sarg[tid])) {
                    smin[tid] = s2; sarg[tid] = a2;
                }
            }
            __syncthreads();
        }
        if (smin[0] < THRESHV) {
            if (tid == 0) {
                uint32_t k = s_nr++;
                myscr[2 * k] = (uint32_t)p;
                myscr[2 * k + 1] = (uint32_t)mapping[sarg[0]];
            }
        }
        __syncthreads();
    }
    __threadfence_block();
    __syncthreads();
    uint32_t nr = s_nr;

    // redundant global max of the exact fixed image
    float gm = -INFINITY;
    for (int i = tid; i < HH * WW * CC; i += 256)
        gm = fmaxf(gm, fixed_val(i, img, mem2, myscr, nr));
    gm = wave_max(gm);
    if (lane == 0) r0[w] = gm;
    __syncthreads();
    if (tid == 0)
        s_ginv = 1.0f / fmaxf(fmaxf(r0[0], r0[1]), fmaxf(r0[2], r0[3]));
    __syncthreads();
    float ginv = s_ginv;

    // exact write of this block's slice (768 elements)
    int base = blockIdx.x * 768;
    for (int i = base + tid; i < base + 768; i += 256)
        out[i] = fixed_val(i, img, mem2, myscr, nr) * ginv;
}

extern "C" void kernel_launch(void* const* d_in, const int* in_sizes, int n_in,
                              void* d_out, int out_size, void* d_ws, size_t ws_size,
                              hipStream_t stream) {
    const float* img      = (const float*)d_in[0];
    const float* mem      = (const float*)d_in[1];
    const float* mem2     = (const float*)d_in[2];
    const long long* mapping = (const long long*)d_in[3];
    float* out    = (float*)d_out;
    uint32_t* wsu = (uint32_t*)d_ws;

    float*    pnorm = (float*)(wsu + OFF_PNORM);
    float*    prmax = (float*)(wsu + OFF_PRMAX);
    float*    prmin = (float*)(wsu + OFF_PRMIN);
    float*    nbmin = (float*)(wsu + OFF_NBMIN);
    float*    nbmax = (float*)(wsu + OFF_NBMAX);
    float*    pmaxA = (float*)(wsu + OFF_PMAXA);
    uint32_t* fbscr = wsu + OFF_FBSCR;

    fused_main<<<NPATCH + 1024, 256, 0, stream>>>(mem, img, pnorm, prmax,
                                                  prmin, nbmin, nbmax, pmaxA);
    finish_k  <<<1024, 256, 0, stream>>>(img, mem, mem2, mapping, pnorm,
                                         prmax, prmin, nbmin, nbmax, pmaxA,
                                         out, fbscr);
}